// Round 2
// baseline (1891.097 us; speedup 1.0000x reference)
//
#include <hip/hip_runtime.h>
#include <stdint.h>

// Forward warp (scatter bilinear splat) reformulated as an ATOMIC-FREE gather.
// img: (N=4, C=3, H=1080, W=1920) fp32
// flo: (N, 2, H, W) fp32; plane0=y (drives COLUMN offset), plane1=x (drives ROW offset).
// Scatter: out[n,c, h+floor(x)+dx, w+floor(y)+dy] += img[n,c,h,w] * wx*wy.
// Gather identity: contribution of source s=(h,w) to output o=(h+a, w+b) is
//   img[s] * tent(x_s - a) * tent(y_s - b),  tent(t) = max(0, 1-|t|),
// nonzero only for |x_s - a| < 1 (resp. y,b). Kernel 1 gathers all taps with
// |a|<=4 && |b|<=4 (sources staged in LDS, accumulate in REGISTERS, each
// output written exactly once -> zero atomics, zero memset).
// Kernel 2 (fixup): rare taps with |a|>4 or |b|>4 (P~1e-4 for N(0,1) flow)
// via global atomics. Coverage test matches kernel 1 exactly.
//
// Round-1 lesson: LDS atomics are lane-serialized (~2.3 cyc/lane through the
// per-CU DS unit); 100M lane-atomics == 539us regardless of occupancy. So: no atomics.

#define N_ 4
#define C_ 3
#define H_ 1080
#define W_ 1920
#define HW_ (H_ * W_)

#define TW 32
#define TH 32
#define HALO 4
#define WW (TW + 2 * HALO)  // 40
#define WH (TH + 2 * HALO)  // 40
#define KSTRIP 4            // output rows per thread
#define NQ (WW / 4)         // 10 float4 quads per window row
#define PLANE_Q (WH * NQ)   // 400 quads per plane

// Gather one source row into the per-thread accumulator strip.
// KMIN/KMAX restrict to taps with |a|<=HALO (a = k + HALO - dr).
template <int KMIN, int KMAX>
__device__ __forceinline__ void gather_row(int wr, int dr, int c,
                                           const float2 (*sxy)[WW],
                                           const float2 (*sc01)[WW],
                                           const float (*sc2)[WW],
                                           float acc[KSTRIP][3]) {
  const float uoff = (float)(dr - HALO);
#pragma unroll
  for (int dc = 0; dc < 9; ++dc) {
    const int wc = c + dc;
    const float2 xy = sxy[wr][wc];  // {x, y}
    // column tent: b = HALO - dc
    const float ty = fmaxf(0.f, 1.f - fabsf(xy.y - (float)(HALO - dc)));
    const float u = xy.x + uoff;  // x - a_k = u - k
    const float2 c01v = sc01[wr][wc];
    const float c2v = sc2[wr][wc];
#pragma unroll
    for (int k = KMIN; k <= KMAX; ++k) {
      const float tx = fmaxf(0.f, 1.f - fabsf(u - (float)k));
      const float w = tx * ty;
      acc[k][0] += c01v.x * w;
      acc[k][1] += c01v.y * w;
      acc[k][2] += c2v * w;
    }
  }
}

__global__ __launch_bounds__(256) void fw_gather_kernel(
    const float* __restrict__ img, const float* __restrict__ flo,
    float* __restrict__ out) {
  __shared__ float2 sxy[WH][WW];   // {x, y}            12.8 KB
  __shared__ float2 sc01[WH][WW];  // {c0, c1}          12.8 KB
  __shared__ float sc2[WH][WW];    // {c2}               6.4 KB

  const int tid = threadIdx.x;
  const int C0 = blockIdx.x * TW;
  const int R0 = blockIdx.y * TH;
  const int n = blockIdx.z;
  const int base = n * C_ * HW_;
  const int fbase = n * 2 * HW_;

  // ---- stage 5 planes (y, x, c0, c1, c2) as float4 quads, zero-fill OOB.
  // Window cols are 4-aligned and W_%4==0, so quad validity is all-or-nothing.
  for (int id = tid; id < 5 * PLANE_Q; id += 256) {
    const int p = id / PLANE_Q;
    const int r = id - p * PLANE_Q;
    const int wr = r / NQ;
    const int q = r - wr * NQ;
    const int h = R0 - HALO + wr;
    const int w0 = C0 - HALO + 4 * q;
    float4 v = make_float4(0.f, 0.f, 0.f, 0.f);
    if ((unsigned)h < H_ && (unsigned)w0 < W_) {
      const float* src = (p == 0)   ? (flo + fbase)          // y plane
                         : (p == 1) ? (flo + fbase + HW_)    // x plane
                                    : (img + base + (p - 2) * HW_);
      v = *reinterpret_cast<const float4*>(src + h * W_ + w0);
    }
    const int wc = 4 * q;
    if (p == 0) {
      sxy[wr][wc + 0].y = v.x;
      sxy[wr][wc + 1].y = v.y;
      sxy[wr][wc + 2].y = v.z;
      sxy[wr][wc + 3].y = v.w;
    } else if (p == 1) {
      sxy[wr][wc + 0].x = v.x;
      sxy[wr][wc + 1].x = v.y;
      sxy[wr][wc + 2].x = v.z;
      sxy[wr][wc + 3].x = v.w;
    } else if (p == 2) {
      sc01[wr][wc + 0].x = v.x;
      sc01[wr][wc + 1].x = v.y;
      sc01[wr][wc + 2].x = v.z;
      sc01[wr][wc + 3].x = v.w;
    } else if (p == 3) {
      sc01[wr][wc + 0].y = v.x;
      sc01[wr][wc + 1].y = v.y;
      sc01[wr][wc + 2].y = v.z;
      sc01[wr][wc + 3].y = v.w;
    } else {
      *reinterpret_cast<float4*>(&sc2[wr][wc]) = v;  // 16B-aligned
    }
  }
  __syncthreads();

  // ---- register gather: thread owns a KSTRIP x 1 output strip
  const int c = tid & (TW - 1);  // output col (tile-local)
  const int rg = tid >> 5;       // row-group 0..7
  const int r0 = rg * KSTRIP;    // first output row of strip

  float acc[KSTRIP][3];
#pragma unroll
  for (int k = 0; k < KSTRIP; ++k) acc[k][0] = acc[k][1] = acc[k][2] = 0.f;

  // Source rows wr = r0+dr, dr in [0,12). Valid taps: dr-8 <= k <= dr.
  gather_row<0, 0>(r0 + 0, 0, c, sxy, sc01, sc2, acc);
  gather_row<0, 1>(r0 + 1, 1, c, sxy, sc01, sc2, acc);
  gather_row<0, 2>(r0 + 2, 2, c, sxy, sc01, sc2, acc);
#pragma unroll
  for (int dr = 3; dr <= 8; ++dr)
    gather_row<0, 3>(r0 + dr, dr, c, sxy, sc01, sc2, acc);
  gather_row<1, 3>(r0 + 9, 9, c, sxy, sc01, sc2, acc);
  gather_row<2, 3>(r0 + 10, 10, c, sxy, sc01, sc2, acc);
  gather_row<3, 3>(r0 + 11, 11, c, sxy, sc01, sc2, acc);

  // ---- store: each output cell owned by exactly one thread
#pragma unroll
  for (int k = 0; k < KSTRIP; ++k) {
    const int h = R0 + r0 + k;
    if (h < H_) {
      const int o = base + h * W_ + C0 + c;
      out[o] = acc[k][0];
      out[o + HW_] = acc[k][1];
      out[o + 2 * HW_] = acc[k][2];
    }
  }
}

// Fixup: taps with target offset outside [-HALO, HALO]^2 (not covered by the
// gather). float4-vectorized fast reject; rare slow path uses global atomics.
__global__ __launch_bounds__(256) void fw_fixup_kernel(
    const float* __restrict__ img, const float* __restrict__ flo,
    float* __restrict__ out) {
  const int t = blockIdx.x * blockDim.x + threadIdx.x;
  if (t >= (N_ * HW_) / 4) return;
  const int idx4 = t * 4;
  const int n = idx4 / HW_;
  const int hw4 = idx4 - n * HW_;  // HW_ % 4 == 0 -> all 4 px in same image

  const float4 yv =
      *reinterpret_cast<const float4*>(flo + (size_t)(n * 2 + 0) * HW_ + hw4);
  const float4 xv =
      *reinterpret_cast<const float4*>(flo + (size_t)(n * 2 + 1) * HW_ + hw4);

  const float ys[4] = {yv.x, yv.y, yv.z, yv.w};
  const float xs[4] = {xv.x, xv.y, xv.z, xv.w};

  // fast reject: x,y in [-HALO, HALO) => all 4 taps have |a|<=HALO, |b|<=HALO
  bool any = false;
#pragma unroll
  for (int k = 0; k < 4; ++k) {
    const bool inside = (xs[k] >= -(float)HALO) && (xs[k] < (float)HALO) &&
                        (ys[k] >= -(float)HALO) && (ys[k] < (float)HALO);
    any |= !inside;
  }
  if (!any) return;

  const int base = n * C_ * HW_;
#pragma unroll 1
  for (int k = 0; k < 4; ++k) {
    const float x = xs[k];
    const float y = ys[k];
    const bool inside = (x >= -(float)HALO) && (x < (float)HALO) &&
                        (y >= -(float)HALO) && (y < (float)HALO);
    if (inside) continue;

    const int hw = hw4 + k;
    const int h = hw / W_;
    const int w = hw - h * W_;
    const float x1 = floorf(x);
    const float y1 = floorf(y);
    const int ix = (int)x1;
    const int iy = (int)y1;
    const float fx = x - x1;
    const float fy = y - y1;
    const float c0 = img[base + 0 * HW_ + hw];
    const float c1 = img[base + 1 * HW_ + hw];
    const float c2 = img[base + 2 * HW_ + hw];

#pragma unroll
    for (int dx = 0; dx < 2; ++dx) {
      const int dh = h + ix + dx;
      if ((unsigned)dh >= H_) continue;
      const float wxw = dx ? fx : (1.0f - fx);
#pragma unroll
      for (int dy = 0; dy < 2; ++dy) {
        const int dw = w + iy + dy;
        if ((unsigned)dw >= W_) continue;
        const int a = ix + dx;  // target row offset
        const int b = iy + dy;  // target col offset
        if (a >= -HALO && a <= HALO && b >= -HALO && b <= HALO)
          continue;  // covered by gather kernel
        const float wt = wxw * (dy ? fy : (1.0f - fy));
        const int o = base + dh * W_ + dw;
        atomicAdd(out + o, c0 * wt);
        atomicAdd(out + o + HW_, c1 * wt);
        atomicAdd(out + o + 2 * HW_, c2 * wt);
      }
    }
  }
}

extern "C" void kernel_launch(void* const* d_in, const int* in_sizes, int n_in,
                              void* d_out, int out_size, void* d_ws,
                              size_t ws_size, hipStream_t stream) {
  const float* img = (const float*)d_in[0];
  const float* flo = (const float*)d_in[1];
  float* out = (float*)d_out;

  // No memset: fw_gather_kernel writes every output element exactly once.
  dim3 grid1(W_ / TW, (H_ + TH - 1) / TH, N_);  // 60 x 34 x 4
  fw_gather_kernel<<<grid1, 256, 0, stream>>>(img, flo, out);

  const int total4 = (N_ * HW_) / 4;
  fw_fixup_kernel<<<(total4 + 255) / 256, 256, 0, stream>>>(img, flo, out);
}

// Round 3
// 352.396 us; speedup vs baseline: 5.3664x; 5.3664x over previous
//
#include <hip/hip_runtime.h>
#include <stdint.h>

// Forward warp (scatter bilinear splat) as an ATOMIC-FREE output gather.
// img: (N=4, C=3, H=1080, W=1920) fp32
// flo: (N, 2, H, W) fp32; plane0=y (COLUMN offset), plane1=x (ROW offset).
// Scatter: out[n,c, h+floor(x)+dx, w+floor(y)+dy] += img[n,c,h,w] * wx*wy.
// Gather identity: source s=(h,w) contributes img[s]*tent(x_s-a)*tent(y_s-b)
// to out(h+a, w+b), tent(t)=max(0,1-|t|). Kernel 1 gathers all taps with
// |a|<=4 && |b|<=4 from an LDS-staged window into REGISTERS (no atomics,
// no memset, each output written once). Kernel 2 fixes up rare |flow|>4
// escapees (P~1e-4) with global atomics, per-tap exclusion -> exact.
//
// Round-1 lesson: LDS atomics lane-serialize (~2.3 cyc/lane); 100M lane
//   atomics = 539us regardless of occupancy -> no atomics in the hot path.
// Round-2 lesson: fully unrolling 12x9 gather => VGPR 256 + ~1.4GB scratch
//   spill traffic at 11% occupancy. This version: looped rows
//   (#pragma unroll 1), compile-time-indexed acc, __launch_bounds__(256,4),
//   and {c0,c1,c2,x} packed float4 so each tap-pair is 1 b128 + 1 b32 LDS op.

#define N_ 4
#define C_ 3
#define H_ 1080
#define W_ 1920
#define HW_ (H_ * W_)

#define TW 32
#define TH 32
#define HALO 4
#define WW (TW + 2 * HALO)  // 40
#define WH (TH + 2 * HALO)  // 40
#define NQ (WW / 4)         // 10 float4 quads per window row
#define PLANE_Q (WH * NQ)   // 400 quads per plane

// Gather one source row into the per-thread 4-row accumulator strip.
// Valid taps need |a|<=HALO, a = k - dr + HALO  =>  dr-8 <= k <= dr.
// MASKED=false only for dr in [3,8] where all k in [0,3] are valid.
template <bool MASKED>
__device__ __forceinline__ void gather_one_row(int wr, int dr, int c,
                                               const float (*spack)[WW][4],
                                               const float (*sy)[WW],
                                               float acc[4][3]) {
  const float uoff = (float)(dr - HALO);
  float m[4];
  if (MASKED) {
#pragma unroll
    for (int k = 0; k < 4; ++k)
      m[k] = ((unsigned)(dr - k) <= 8u) ? 1.0f : 0.0f;
  }
#pragma unroll
  for (int dc = 0; dc < 9; ++dc) {
    const int wc = c + dc;
    const float4 f = *reinterpret_cast<const float4*>(&spack[wr][wc][0]);
    const float yv = sy[wr][wc];
    // column tent: b = HALO - dc
    const float ty = fmaxf(0.f, 1.f - fabsf(yv - (float)(HALO - dc)));
    const float u = f.w + uoff;  // x - a_k = u - k
#pragma unroll
    for (int k = 0; k < 4; ++k) {
      float txy = fmaxf(0.f, 1.f - fabsf(u - (float)k)) * ty;
      if (MASKED) txy *= m[k];
      acc[k][0] = fmaf(f.x, txy, acc[k][0]);
      acc[k][1] = fmaf(f.y, txy, acc[k][1]);
      acc[k][2] = fmaf(f.z, txy, acc[k][2]);
    }
  }
}

__global__ __launch_bounds__(256, 4) void fw_gather_kernel(
    const float* __restrict__ img, const float* __restrict__ flo,
    float* __restrict__ out) {
  __shared__ float spack[WH][WW][4];  // {c0,c1,c2,x}  25.6 KB
  __shared__ float sy[WH][WW];        // {y}            6.4 KB

  const int tid = threadIdx.x;
  const int C0 = blockIdx.x * TW;
  const int R0 = blockIdx.y * TH;
  const int n = blockIdx.z;
  const int base = n * C_ * HW_;
  const int fbase = n * 2 * HW_;

  // ---- stage 5 planes (y, x, c0, c1, c2) via float4 loads, zero-fill OOB.
  // Window cols are 4-aligned and W_%4==0 -> quad validity all-or-nothing.
  for (int id = tid; id < 5 * PLANE_Q; id += 256) {
    const int p = id / PLANE_Q;
    const int r = id - p * PLANE_Q;
    const int wr = r / NQ;
    const int q = r - wr * NQ;
    const int h = R0 - HALO + wr;
    const int w0 = C0 - HALO + 4 * q;
    float4 v = make_float4(0.f, 0.f, 0.f, 0.f);
    if ((unsigned)h < H_ && (unsigned)w0 < W_) {
      const float* src = (p == 0)   ? (flo + fbase)        // y plane
                         : (p == 1) ? (flo + fbase + HW_)  // x plane
                                    : (img + base + (p - 2) * HW_);
      v = *reinterpret_cast<const float4*>(src + h * W_ + w0);
    }
    const int wc = 4 * q;
    if (p == 0) {
      sy[wr][wc + 0] = v.x;
      sy[wr][wc + 1] = v.y;
      sy[wr][wc + 2] = v.z;
      sy[wr][wc + 3] = v.w;
    } else {
      const int ch = (p == 1) ? 3 : (p - 2);
      spack[wr][wc + 0][ch] = v.x;
      spack[wr][wc + 1][ch] = v.y;
      spack[wr][wc + 2][ch] = v.z;
      spack[wr][wc + 3][ch] = v.w;
    }
  }
  __syncthreads();

  // ---- register gather: thread owns a 4-row x 1-col output strip
  const int c = tid & (TW - 1);  // output col (tile-local)
  const int r0 = (tid >> 5) * 4; // first output row of strip

  float acc[4][3];
#pragma unroll
  for (int k = 0; k < 4; ++k) acc[k][0] = acc[k][1] = acc[k][2] = 0.f;

  // Source rows wr = r0 + dr, dr in [0,12). Looped (NOT unrolled) to keep
  // register pressure bounded; inner 9x4 taps fully unrolled (static idx).
#pragma unroll 1
  for (int dr = 0; dr < 3; ++dr)
    gather_one_row<true>(r0 + dr, dr, c, spack, sy, acc);
#pragma unroll 1
  for (int dr = 3; dr < 9; ++dr)
    gather_one_row<false>(r0 + dr, dr, c, spack, sy, acc);
#pragma unroll 1
  for (int dr = 9; dr < 12; ++dr)
    gather_one_row<true>(r0 + dr, dr, c, spack, sy, acc);

  // ---- store: each output cell owned by exactly one thread
#pragma unroll
  for (int k = 0; k < 4; ++k) {
    const int h = R0 + r0 + k;
    if (h < H_) {
      const int o = base + h * W_ + C0 + c;
      out[o] = acc[k][0];
      out[o + HW_] = acc[k][1];
      out[o + 2 * HW_] = acc[k][2];
    }
  }
}

// Fixup: taps with target offset outside [-HALO, HALO]^2 (not covered by the
// gather). float4-vectorized fast reject; rare slow path uses global atomics.
__global__ __launch_bounds__(256) void fw_fixup_kernel(
    const float* __restrict__ img, const float* __restrict__ flo,
    float* __restrict__ out) {
  const int t = blockIdx.x * blockDim.x + threadIdx.x;
  if (t >= (N_ * HW_) / 4) return;
  const int idx4 = t * 4;
  const int n = idx4 / HW_;
  const int hw4 = idx4 - n * HW_;  // HW_ % 4 == 0 -> all 4 px in same image

  const float4 yv =
      *reinterpret_cast<const float4*>(flo + (size_t)(n * 2 + 0) * HW_ + hw4);
  const float4 xv =
      *reinterpret_cast<const float4*>(flo + (size_t)(n * 2 + 1) * HW_ + hw4);

  const float ys[4] = {yv.x, yv.y, yv.z, yv.w};
  const float xs[4] = {xv.x, xv.y, xv.z, xv.w};

  // fast reject: x,y in [-HALO, HALO) => all 4 taps have |a|<=HALO, |b|<=HALO
  bool any = false;
#pragma unroll
  for (int k = 0; k < 4; ++k) {
    const bool inside = (xs[k] >= -(float)HALO) && (xs[k] < (float)HALO) &&
                        (ys[k] >= -(float)HALO) && (ys[k] < (float)HALO);
    any |= !inside;
  }
  if (!any) return;

  const int base = n * C_ * HW_;
#pragma unroll 1
  for (int k = 0; k < 4; ++k) {
    const float x = xs[k];
    const float y = ys[k];
    const bool inside = (x >= -(float)HALO) && (x < (float)HALO) &&
                        (y >= -(float)HALO) && (y < (float)HALO);
    if (inside) continue;

    const int hw = hw4 + k;
    const int h = hw / W_;
    const int w = hw - h * W_;
    const float x1 = floorf(x);
    const float y1 = floorf(y);
    const int ix = (int)x1;
    const int iy = (int)y1;
    const float fx = x - x1;
    const float fy = y - y1;
    const float c0 = img[base + 0 * HW_ + hw];
    const float c1 = img[base + 1 * HW_ + hw];
    const float c2 = img[base + 2 * HW_ + hw];

#pragma unroll
    for (int dx = 0; dx < 2; ++dx) {
      const int dh = h + ix + dx;
      if ((unsigned)dh >= H_) continue;
      const float wxw = dx ? fx : (1.0f - fx);
#pragma unroll
      for (int dy = 0; dy < 2; ++dy) {
        const int dw = w + iy + dy;
        if ((unsigned)dw >= W_) continue;
        const int a = ix + dx;  // target row offset
        const int b = iy + dy;  // target col offset
        if (a >= -HALO && a <= HALO && b >= -HALO && b <= HALO)
          continue;  // covered by gather kernel
        const float wt = wxw * (dy ? fy : (1.0f - fy));
        const int o = base + dh * W_ + dw;
        atomicAdd(out + o, c0 * wt);
        atomicAdd(out + o + HW_, c1 * wt);
        atomicAdd(out + o + 2 * HW_, c2 * wt);
      }
    }
  }
}

extern "C" void kernel_launch(void* const* d_in, const int* in_sizes, int n_in,
                              void* d_out, int out_size, void* d_ws,
                              size_t ws_size, hipStream_t stream) {
  const float* img = (const float*)d_in[0];
  const float* flo = (const float*)d_in[1];
  float* out = (float*)d_out;

  // No memset: fw_gather_kernel writes every output element exactly once.
  dim3 grid1(W_ / TW, (H_ + TH - 1) / TH, N_);  // 60 x 34 x 4
  fw_gather_kernel<<<grid1, 256, 0, stream>>>(img, flo, out);

  const int total4 = (N_ * HW_) / 4;
  fw_fixup_kernel<<<(total4 + 255) / 256, 256, 0, stream>>>(img, flo, out);
}